// Round 1
// baseline (1059.610 us; speedup 1.0000x reference)
//
#include <hip/hip_runtime.h>

#define HDIM 4096
#define BDIM 32
#define BH (BDIM * HDIM)

typedef short short8 __attribute__((ext_vector_type(8)));
typedef float float4v __attribute__((ext_vector_type(4)));

__device__ __forceinline__ short f2bf_rne(float f) {
    unsigned u = __builtin_bit_cast(unsigned, f);
    return (short)((u + 0x7fffu + ((u >> 16) & 1u)) >> 16);
}

// fp32 -> bf16 for activations: x (B*H) and prev_h (L*B*H), 3*BH elements total
__global__ __launch_bounds__(512) void convert_kernel(
    const float* __restrict__ x, const float* __restrict__ ph_f,
    short* __restrict__ x0, short* __restrict__ ph) {
    int idx = blockIdx.x * 512 + threadIdx.x;
    if (idx < BH) {
        x0[idx] = f2bf_rne(x[idx]);
    } else {
        int j = idx - BH;
        ph[j] = f2bf_rne(ph_f[j]);
    }
}

// One LSTM layer. Block = 16 hidden units (u0..u0+15), all 4 gates, all 32 batch.
// 8 waves: wv 0..3 -> x @ W_ih^T (gate wv), wv 4..7 -> h @ W_hh^T (gate wv-3... wv&3).
// Weights read fp32, split into bf16 hi + residual lo, 2 chained MFMAs each
// (error from dropped lo*lo term ~2^-16 rel -- effectively fp32-accurate weights).
__global__ __launch_bounds__(512) void lstm_layer_kernel(
    const float* __restrict__ W_ih, const float* __restrict__ W_hh,
    const float* __restrict__ b_ih, const float* __restrict__ b_hh,
    const float* __restrict__ prev_c,
    const short* __restrict__ x_bf, const short* __restrict__ h_bf,
    float* __restrict__ out_h, float* __restrict__ out_c,
    short* __restrict__ x_next) {
    __shared__ float lds[8 * 32 * 16];

    const int tid  = threadIdx.x;
    const int wv   = tid >> 6;       // wave 0..7
    const int lane = tid & 63;
    const int g    = wv & 3;         // gate index (i,f,g,o)
    const float* __restrict__ Wm = (wv < 4) ? W_ih : W_hh;
    const short* __restrict__ Am = (wv < 4) ? x_bf : h_bf;

    const int u0   = blockIdx.x * 16;
    const int nsel = lane & 15;      // A: batch row within tile / B: weight row (col)
    const int koff = lane >> 4;      // k-group 0..3, 8 elements each

    const float* pw  = Wm + (size_t)(g * HDIM + u0 + nsel) * HDIM + koff * 8;
    const short* pa0 = Am + (size_t)(0 + nsel) * HDIM + koff * 8;
    const short* pa1 = Am + (size_t)(16 + nsel) * HDIM + koff * 8;

    float4v acc0 = {0.f, 0.f, 0.f, 0.f};   // batch rows 0..15
    float4v acc1 = {0.f, 0.f, 0.f, 0.f};   // batch rows 16..31

#pragma unroll 4
    for (int kb = 0; kb < HDIM / 32; ++kb) {
        float4v w0 = __builtin_nontemporal_load((const float4v*)pw);
        float4v w1 = __builtin_nontemporal_load((const float4v*)(pw + 4));
        short8 a0 = *(const short8*)pa0;
        short8 a1 = *(const short8*)pa1;

        short8 whi, wlo;
        float wf[8];
        wf[0] = w0[0]; wf[1] = w0[1]; wf[2] = w0[2]; wf[3] = w0[3];
        wf[4] = w1[0]; wf[5] = w1[1]; wf[6] = w1[2]; wf[7] = w1[3];
#pragma unroll
        for (int i = 0; i < 8; ++i) {
            unsigned u  = __builtin_bit_cast(unsigned, wf[i]);
            unsigned rh = u & 0xffff0000u;            // truncated hi
            float fhi   = __builtin_bit_cast(float, rh);
            float flo   = wf[i] - fhi;                 // exact residual
            whi[i] = (short)(rh >> 16);
            wlo[i] = (short)(__builtin_bit_cast(unsigned, flo) >> 16);
        }

        acc0 = __builtin_amdgcn_mfma_f32_16x16x32_bf16(a0, whi, acc0, 0, 0, 0);
        acc1 = __builtin_amdgcn_mfma_f32_16x16x32_bf16(a1, whi, acc1, 0, 0, 0);
        acc0 = __builtin_amdgcn_mfma_f32_16x16x32_bf16(a0, wlo, acc0, 0, 0, 0);
        acc1 = __builtin_amdgcn_mfma_f32_16x16x32_bf16(a1, wlo, acc1, 0, 0, 0);

        pw += 32; pa0 += 32; pa1 += 32;
    }

    // C/D layout: col = lane&15 (hidden unit), row = (lane>>4)*4 + reg (batch)
    {
        const int q = lane >> 4;
        const int c = lane & 15;
#pragma unroll
        for (int r = 0; r < 4; ++r) {
            lds[(wv * 32 + q * 4 + r) * 16 + c]      = acc0[r];
            lds[(wv * 32 + 16 + q * 4 + r) * 16 + c] = acc1[r];
        }
    }
    __syncthreads();

    // elementwise LSTM: 512 threads = 32 batch x 16 units
    const int u = tid & 15;
    const int b = tid >> 4;
    float gv[4];
#pragma unroll
    for (int gg = 0; gg < 4; ++gg) {
        gv[gg] = lds[(gg * 32 + b) * 16 + u] + lds[((4 + gg) * 32 + b) * 16 + u]
               + b_ih[gg * HDIM + u0 + u] + b_hh[gg * HDIM + u0 + u];
    }
    const float ig = 1.f / (1.f + expf(-gv[0]));
    const float fg = 1.f / (1.f + expf(-gv[1]));
    const float gt = tanhf(gv[2]);
    const float og = 1.f / (1.f + expf(-gv[3]));

    const int off  = b * HDIM + u0 + u;
    const float cp = prev_c[off];
    const float cn = fg * cp + ig * gt;
    const float hn = og * tanhf(cn);

    out_h[off]  = hn;
    out_c[off]  = cn;
    x_next[off] = f2bf_rne(hn);   // bf16 input for next layer
}

extern "C" void kernel_launch(void* const* d_in, const int* in_sizes, int n_in,
                              void* d_out, int out_size, void* d_ws, size_t ws_size,
                              hipStream_t stream) {
    const float* inputs = (const float*)d_in[0];   // [B,H]
    const float* prev_h = (const float*)d_in[1];   // [L,B,H]
    const float* prev_c = (const float*)d_in[2];   // [L,B,H]
    const float* W_ih   = (const float*)d_in[3];   // [L,4H,H]
    const float* W_hh   = (const float*)d_in[4];   // [L,4H,H]
    const float* b_ih   = (const float*)d_in[5];   // [L,4H]
    const float* b_hh   = (const float*)d_in[6];   // [L,4H]
    float* out = (float*)d_out;                    // [2,L,B,H]

    short* ws = (short*)d_ws;
    short* x0 = ws;            // bf16 layer-0 input  (BH shorts)
    short* x1 = ws + BH;       // bf16 layer-1 input  (BH shorts)
    short* ph = ws + 2 * BH;   // bf16 prev_h, both layers (2*BH shorts)

    // 3*BH = 393216 = 768 * 512
    convert_kernel<<<768, 512, 0, stream>>>(inputs, prev_h, x0, ph);

    const size_t WL = (size_t)4 * HDIM * HDIM;     // per-layer weight stride

    // layer 0: out_h -> out[0,0], out_c -> out[1,0]
    lstm_layer_kernel<<<256, 512, 0, stream>>>(
        W_ih, W_hh, b_ih, b_hh, prev_c,
        x0, ph, out + 0 * BH, out + 2 * BH, x1);

    // layer 1: x = layer-0 h; out_h -> out[0,1], out_c -> out[1,1]
    lstm_layer_kernel<<<256, 512, 0, stream>>>(
        W_ih + WL, W_hh + WL, b_ih + 4 * HDIM, b_hh + 4 * HDIM, prev_c + BH,
        x1, ph + BH, out + 1 * BH, out + 3 * BH, x0 /*scratch, unused*/);
}